// Round 1
// baseline (2231.874 us; speedup 1.0000x reference)
//
#include <hip/hip_runtime.h>
#include <hip/hip_bf16.h>
#include <math.h>

#define BH    64
#define NSEQ  4096
#define DDIM  64
#define MDIM  266
#define NCH   5            // column chunks of 64 (last has 10)
#define RATIO 0.06131393394849658f   // 1/sqrt(266)
#define NORMF 0.35355339059327373f   // 64^-0.25
#define DIAGF 0.0625f                // 0.5 * 64^-0.5
#define EPSF  1e-4f

__device__ __forceinline__ unsigned fenc(float f) {
  unsigned u = __float_as_uint(f);
  return (u & 0x80000000u) ? ~u : (u | 0x80000000u);
}
__device__ __forceinline__ float fdec(unsigned u) {
  return (u & 0x80000000u) ? __uint_as_float(u & 0x7fffffffu) : __uint_as_float(~u);
}

// ---------------------------------------------------------------------------
// Kernel A: global max of k_dash = NORMF * (K . P^T) over [BH, N, M]
// 128 rows/block, thread tile 8 rows x 4 cols (rows = ty+16i, cols = tx+16cc)
// ---------------------------------------------------------------------------
__global__ __launch_bounds__(256) void kmax_kernel(const float* __restrict__ k,
                                                   const float* __restrict__ proj,
                                                   unsigned* __restrict__ kmax) {
  __shared__ float sK[128 * 76];
  __shared__ float sP[64 * 76];
  const int tid = threadIdx.x, tx = tid & 15, ty = tid >> 4;
  const int bh = blockIdx.x >> 5, ch = blockIdx.x & 31;
  const float* kb = k + ((size_t)bh * NSEQ + (size_t)ch * 128) * DDIM;

  for (int t = 0; t < 8; ++t) {
    int fid = tid + t * 256;           // 2048 float4
    int r = fid >> 4, d4 = fid & 15;
    float4 v = ((const float4*)kb)[fid];
    *(float4*)&sK[r * 76 + d4 * 4] = v;
  }

  float tmax = -1e30f;
  for (int c = 0; c < NCH; ++c) {
    const int j0 = c * 64, jn = min(64, MDIM - j0);
    __syncthreads();
    for (int t = 0; t < 4; ++t) {
      int fid = tid + t * 256;
      int jj = fid >> 4, d4 = fid & 15;
      float4 pv = (jj < jn) ? ((const float4*)(proj + (size_t)(j0 + jj) * DDIM))[d4]
                            : make_float4(0.f, 0.f, 0.f, 0.f);
      *(float4*)&sP[jj * 76 + d4 * 4] = pv;
    }
    __syncthreads();

    float acc[8][4];
#pragma unroll
    for (int i = 0; i < 8; ++i)
#pragma unroll
      for (int cc = 0; cc < 4; ++cc) acc[i][cc] = 0.f;

    for (int kk = 0; kk < 64; kk += 4) {
      float4 pv[4], kv[8];
#pragma unroll
      for (int cc = 0; cc < 4; ++cc) pv[cc] = *(const float4*)&sP[(tx + 16 * cc) * 76 + kk];
#pragma unroll
      for (int i = 0; i < 8; ++i) kv[i] = *(const float4*)&sK[(ty + 16 * i) * 76 + kk];
#pragma unroll
      for (int i = 0; i < 8; ++i)
#pragma unroll
        for (int cc = 0; cc < 4; ++cc) {
          acc[i][cc] = fmaf(kv[i].x, pv[cc].x, acc[i][cc]);
          acc[i][cc] = fmaf(kv[i].y, pv[cc].y, acc[i][cc]);
          acc[i][cc] = fmaf(kv[i].z, pv[cc].z, acc[i][cc]);
          acc[i][cc] = fmaf(kv[i].w, pv[cc].w, acc[i][cc]);
        }
    }
#pragma unroll
    for (int cc = 0; cc < 4; ++cc) {
      if (tx + 16 * cc < jn) {
#pragma unroll
        for (int i = 0; i < 8; ++i) tmax = fmaxf(tmax, acc[i][cc]);
      }
    }
  }
#pragma unroll
  for (int off = 32; off; off >>= 1) tmax = fmaxf(tmax, __shfl_xor(tmax, off));
  if ((tid & 63) == 0) atomicMax(kmax, fenc(tmax * NORMF));
}

// ---------------------------------------------------------------------------
// Kernel B: context[bh][j][e] += sum_n k'[n,j] v[n,e];  ksum[bh][j] += sum_n k'[n,j]
// 512 rows/block (4 tiles of 128); chunk loop outer (5), row tiles inner.
// ---------------------------------------------------------------------------
__global__ __launch_bounds__(256) void ctx_kernel(const float* __restrict__ k,
                                                  const float* __restrict__ v,
                                                  const float* __restrict__ proj,
                                                  const unsigned* __restrict__ kmaxp,
                                                  float* __restrict__ ctx,
                                                  float* __restrict__ ksum) {
  __shared__ float sK[128 * 76];   // K tile; reused (stride 68) as k' buffer
  __shared__ float sV[128 * 68];
  __shared__ float sP[64 * 76];
  __shared__ float sDiag[128];
  const int tid = threadIdx.x, tx = tid & 15, ty = tid >> 4;
  const int bh = blockIdx.x >> 3, c8 = blockIdx.x & 7;
  const float stab = fdec(*kmaxp);
  const float* kb = k + ((size_t)bh * NSEQ + (size_t)c8 * 512) * DDIM;
  const float* vb = v + ((size_t)bh * NSEQ + (size_t)c8 * 512) * DDIM;

  for (int c = 0; c < NCH; ++c) {
    const int j0 = c * 64;
    __syncthreads();
    for (int t = 0; t < 4; ++t) {
      int fid = tid + t * 256;
      int jj = fid >> 4, d4 = fid & 15;
      const int jn = min(64, MDIM - j0);
      float4 pv = (jj < jn) ? ((const float4*)(proj + (size_t)(j0 + jj) * DDIM))[d4]
                            : make_float4(0.f, 0.f, 0.f, 0.f);
      *(float4*)&sP[jj * 76 + d4 * 4] = pv;
    }

    float accC[4][4];
#pragma unroll
    for (int a = 0; a < 4; ++a)
#pragma unroll
      for (int b = 0; b < 4; ++b) accC[a][b] = 0.f;
    float ks = 0.f;

    for (int rt = 0; rt < 4; ++rt) {
      __syncthreads();
      for (int t = 0; t < 8; ++t) {
        int fid = tid + t * 256;
        int r = fid >> 4, d4 = fid & 15;
        float4 kv4 = ((const float4*)(kb + (size_t)rt * 128 * DDIM))[fid];
        float4 vv4 = ((const float4*)(vb + (size_t)rt * 128 * DDIM))[fid];
        *(float4*)&sK[r * 76 + d4 * 4] = kv4;
        *(float4*)&sV[r * 68 + d4 * 4] = vv4;
      }
      __syncthreads();
      if (tid < 128) {
        float s = 0.f;
        for (int d = 0; d < 64; ++d) { float x = sK[tid * 76 + d]; s = fmaf(x, x, s); }
        sDiag[tid] = s * DIAGF;
      }
      __syncthreads();

      float acc1[8][4];
#pragma unroll
      for (int i = 0; i < 8; ++i)
#pragma unroll
        for (int cc = 0; cc < 4; ++cc) acc1[i][cc] = 0.f;

      for (int kk = 0; kk < 64; kk += 4) {
        float4 pv[4], kv[8];
#pragma unroll
        for (int cc = 0; cc < 4; ++cc) pv[cc] = *(const float4*)&sP[(tx + 16 * cc) * 76 + kk];
#pragma unroll
        for (int i = 0; i < 8; ++i) kv[i] = *(const float4*)&sK[(ty + 16 * i) * 76 + kk];
#pragma unroll
        for (int i = 0; i < 8; ++i)
#pragma unroll
          for (int cc = 0; cc < 4; ++cc) {
            acc1[i][cc] = fmaf(kv[i].x, pv[cc].x, acc1[i][cc]);
            acc1[i][cc] = fmaf(kv[i].y, pv[cc].y, acc1[i][cc]);
            acc1[i][cc] = fmaf(kv[i].z, pv[cc].z, acc1[i][cc]);
            acc1[i][cc] = fmaf(kv[i].w, pv[cc].w, acc1[i][cc]);
          }
      }
      __syncthreads();   // everyone done reading sK -> overwrite with k'
#pragma unroll
      for (int i = 0; i < 8; ++i) {
        const int r = ty + 16 * i;
        const float dg = sDiag[r];
#pragma unroll
        for (int cc = 0; cc < 4; ++cc) {
          const int cl = tx + 16 * cc;
          float kd = acc1[i][cc] * NORMF;
          float kp = (j0 + cl < MDIM) ? RATIO * (__expf(kd - dg - stab) + EPSF) : 0.f;
          sK[r * 68 + cl] = kp;
        }
      }
      __syncthreads();

#pragma unroll 4
      for (int r = 0; r < 128; ++r) {
        float4 kp4 = *(const float4*)&sK[r * 68 + ty * 4];
        float4 vv = *(const float4*)&sV[r * 68 + tx * 4];
        float kpj[4] = {kp4.x, kp4.y, kp4.z, kp4.w};
        float ve[4] = {vv.x, vv.y, vv.z, vv.w};
#pragma unroll
        for (int a = 0; a < 4; ++a)
#pragma unroll
          for (int b = 0; b < 4; ++b) accC[a][b] = fmaf(kpj[a], ve[b], accC[a][b]);
      }
      if (tid < 64) {
        float s = 0.f;
        for (int r = 0; r < 128; ++r) s += sK[r * 68 + tid];
        ks += s;
      }
    }
    // accumulate to global
#pragma unroll
    for (int a = 0; a < 4; ++a) {
      const int jg = j0 + ty * 4 + a;
      if (jg < MDIM) {
#pragma unroll
        for (int b = 0; b < 4; ++b)
          atomicAdd(&ctx[((size_t)bh * MDIM + jg) * DDIM + tx * 4 + b], accC[a][b]);
      }
    }
    if (tid < 64 && j0 + tid < MDIM) atomicAdd(&ksum[(size_t)bh * MDIM + j0 + tid], ks);
  }
}

// ---------------------------------------------------------------------------
// Kernel C: q' (with per-row stab) -> out = (q' @ ctx) * Dinv
// 64 rows/block; q_dash materialized in LDS [64][272].
// ---------------------------------------------------------------------------
__global__ __launch_bounds__(256) void out_kernel(const float* __restrict__ q,
                                                  const float* __restrict__ proj,
                                                  const float* __restrict__ ctx,
                                                  const float* __restrict__ ksum,
                                                  float* __restrict__ out) {
  __shared__ float sP[64 * 76];     // proj chunk; later ctx chunk (stride 68)
  __shared__ float sQ[64 * 76];
  __shared__ float sQD[64 * 272];
  __shared__ float sDiag[64], sStab[64], sDinv[64], sKs[272];
  const int tid = threadIdx.x, tx = tid & 15, ty = tid >> 4;
  const int bh = blockIdx.x >> 6, rc = blockIdx.x & 63;
  const float* qb = q + ((size_t)bh * NSEQ + (size_t)rc * 64) * DDIM;

  for (int t = 0; t < 4; ++t) {
    int fid = tid + t * 256;
    int r = fid >> 4, d4 = fid & 15;
    *(float4*)&sQ[r * 76 + d4 * 4] = ((const float4*)qb)[fid];
  }
  for (int t = tid; t < 272; t += 256) sKs[t] = (t < MDIM) ? ksum[(size_t)bh * MDIM + t] : 0.f;
  __syncthreads();
  if (tid < 64) {
    float s = 0.f;
    for (int d = 0; d < 64; ++d) { float x = sQ[tid * 76 + d]; s = fmaf(x, x, s); }
    sDiag[tid] = s * DIAGF;
  }

  for (int c = 0; c < NCH; ++c) {
    const int j0 = c * 64, jn = min(64, MDIM - j0);
    __syncthreads();
    for (int t = 0; t < 4; ++t) {
      int fid = tid + t * 256;
      int jj = fid >> 4, d4 = fid & 15;
      float4 pv = (jj < jn) ? ((const float4*)(proj + (size_t)(j0 + jj) * DDIM))[d4]
                            : make_float4(0.f, 0.f, 0.f, 0.f);
      *(float4*)&sP[jj * 76 + d4 * 4] = pv;
    }
    __syncthreads();

    float acc1[4][4];
#pragma unroll
    for (int i = 0; i < 4; ++i)
#pragma unroll
      for (int cc = 0; cc < 4; ++cc) acc1[i][cc] = 0.f;

    for (int kk = 0; kk < 64; kk += 4) {
      float4 pv[4], kv[4];
#pragma unroll
      for (int cc = 0; cc < 4; ++cc) pv[cc] = *(const float4*)&sP[(tx + 16 * cc) * 76 + kk];
#pragma unroll
      for (int i = 0; i < 4; ++i) kv[i] = *(const float4*)&sQ[(ty + 16 * i) * 76 + kk];
#pragma unroll
      for (int i = 0; i < 4; ++i)
#pragma unroll
        for (int cc = 0; cc < 4; ++cc) {
          acc1[i][cc] = fmaf(kv[i].x, pv[cc].x, acc1[i][cc]);
          acc1[i][cc] = fmaf(kv[i].y, pv[cc].y, acc1[i][cc]);
          acc1[i][cc] = fmaf(kv[i].z, pv[cc].z, acc1[i][cc]);
          acc1[i][cc] = fmaf(kv[i].w, pv[cc].w, acc1[i][cc]);
        }
    }
#pragma unroll
    for (int i = 0; i < 4; ++i)
#pragma unroll
      for (int cc = 0; cc < 4; ++cc) {
        const int jg = j0 + tx + 16 * cc;
        if (jg < MDIM) sQD[(ty + 16 * i) * 272 + jg] = acc1[i][cc] * NORMF;
      }
  }
  __syncthreads();
  // per-row max (stab), 4 lanes per row
  {
    const int r = tid >> 2, p = tid & 3;
    float m = -1e30f;
    for (int j = p; j < MDIM; j += 4) m = fmaxf(m, sQD[r * 272 + j]);
    m = fmaxf(m, __shfl_xor(m, 1));
    m = fmaxf(m, __shfl_xor(m, 2));
    if (p == 0) sStab[r] = m;
  }
  __syncthreads();
  {
    const int r = tid >> 2, p = tid & 3;
    const float dg = sDiag[r], st = sStab[r];
    for (int j = p; j < MDIM; j += 4) {
      float val = RATIO * (__expf(sQD[r * 272 + j] - dg - st) + EPSF);
      sQD[r * 272 + j] = val;
    }
  }
  __syncthreads();
  {
    const int r = tid >> 2, p = tid & 3;
    float s = 0.f;
    for (int j = p; j < MDIM; j += 4) s = fmaf(sQD[r * 272 + j], sKs[j], s);
    s += __shfl_xor(s, 1);
    s += __shfl_xor(s, 2);
    if (p == 0) sDinv[r] = 1.0f / s;
  }

  float accO[4][4];
#pragma unroll
  for (int i = 0; i < 4; ++i)
#pragma unroll
    for (int e = 0; e < 4; ++e) accO[i][e] = 0.f;

  for (int c = 0; c < NCH; ++c) {
    const int j0 = c * 64, jn = min(64, MDIM - j0);
    __syncthreads();
    for (int t = 0; t < 4; ++t) {
      int fid = tid + t * 256;
      int jj = fid >> 4, d4 = fid & 15;
      if (jj < jn)
        *(float4*)&sP[jj * 68 + d4 * 4] =
            ((const float4*)(ctx + ((size_t)bh * MDIM + j0 + jj) * DDIM))[d4];
    }
    __syncthreads();
    for (int jj = 0; jj < jn; ++jj) {
      float4 cv = *(const float4*)&sP[jj * 68 + tx * 4];
      float qv[4];
#pragma unroll
      for (int i = 0; i < 4; ++i) qv[i] = sQD[(ty + 16 * i) * 272 + j0 + jj];
#pragma unroll
      for (int i = 0; i < 4; ++i) {
        accO[i][0] = fmaf(qv[i], cv.x, accO[i][0]);
        accO[i][1] = fmaf(qv[i], cv.y, accO[i][1]);
        accO[i][2] = fmaf(qv[i], cv.z, accO[i][2]);
        accO[i][3] = fmaf(qv[i], cv.w, accO[i][3]);
      }
    }
  }
#pragma unroll
  for (int i = 0; i < 4; ++i) {
    const int r = ty + 16 * i;
    const float di = sDinv[r];
    float4 o = make_float4(accO[i][0] * di, accO[i][1] * di, accO[i][2] * di, accO[i][3] * di);
    *(float4*)&out[((size_t)bh * NSEQ + (size_t)rc * 64 + r) * DDIM + tx * 4] = o;
  }
}

extern "C" void kernel_launch(void* const* d_in, const int* in_sizes, int n_in,
                              void* d_out, int out_size, void* d_ws, size_t ws_size,
                              hipStream_t stream) {
  (void)in_sizes; (void)n_in; (void)out_size; (void)ws_size;
  const float* q = (const float*)d_in[0];
  const float* k = (const float*)d_in[1];
  const float* v = (const float*)d_in[2];
  const float* proj = (const float*)d_in[3];
  float* out = (float*)d_out;

  unsigned* kmax = (unsigned*)d_ws;
  float* ctx = (float*)((char*)d_ws + 256);
  float* ksum = (float*)((char*)d_ws + 256 + (size_t)BH * MDIM * DDIM * 4);
  const size_t ws_used = 256 + (size_t)BH * MDIM * DDIM * 4 + (size_t)BH * MDIM * 4;

  hipMemsetAsync(d_ws, 0, ws_used, stream);
  kmax_kernel<<<dim3(BH * 32), dim3(256), 0, stream>>>(k, proj, kmax);
  ctx_kernel<<<dim3(BH * 8), dim3(256), 0, stream>>>(k, v, proj, kmax, ctx, ksum);
  out_kernel<<<dim3(BH * 64), dim3(256), 0, stream>>>(q, proj, ctx, ksum, out);
}

// Round 2
// 985.996 us; speedup vs baseline: 2.2636x; 2.2636x over previous
//
#include <hip/hip_runtime.h>
#include <math.h>

#define BH    64
#define NSEQ  4096
#define DDIM  64
#define MDIM  266
#define NCH   5
#define RATIO 0.06131393394849658f   // 1/sqrt(266)
#define NORMF 0.35355339059327373f   // 64^-0.25
#define DIAGF 0.0625f                // 0.5 * 64^-0.5
#define EPSF  1e-4f

__device__ __forceinline__ unsigned fenc(float f) {
  unsigned u = __float_as_uint(f);
  return (u & 0x80000000u) ? ~u : (u | 0x80000000u);
}
__device__ __forceinline__ float fdec(unsigned u) {
  return (u & 0x80000000u) ? __uint_as_float(u & 0x7fffffffu) : __uint_as_float(~u);
}

// ---------------------------------------------------------------------------
// Kernel A: global max of k_dash = NORMF*(K.P^T). 64-row tiles, 4x4/thread.
// LDS 39 KB -> 4 blocks/CU.
// ---------------------------------------------------------------------------
__global__ __launch_bounds__(256) void kmax_kernel(const float* __restrict__ k,
                                                   const float* __restrict__ proj,
                                                   unsigned* __restrict__ kmax) {
  __shared__ float sK[64 * 76];
  __shared__ float sP[64 * 76];
  const int tid = threadIdx.x, tx = tid & 15, ty = tid >> 4;
  const int bh = blockIdx.x >> 6, ch = blockIdx.x & 63;
  const float* kb = k + ((size_t)bh * NSEQ + (size_t)ch * 64) * DDIM;

#pragma unroll
  for (int t = 0; t < 4; ++t) {
    int fid = tid + t * 256, r = fid >> 4, d4 = fid & 15;
    *(float4*)&sK[r * 76 + d4 * 4] = ((const float4*)kb)[fid];
  }

  float tmax = -1e30f;
  for (int c = 0; c < NCH; ++c) {
    const int j0 = c * 64, jn = min(64, MDIM - j0);
    __syncthreads();
#pragma unroll
    for (int t = 0; t < 4; ++t) {
      int fid = tid + t * 256, jj = fid >> 4, d4 = fid & 15;
      float4 pv = (jj < jn) ? ((const float4*)(proj + (size_t)(j0 + jj) * DDIM))[d4]
                            : make_float4(0.f, 0.f, 0.f, 0.f);
      *(float4*)&sP[jj * 76 + d4 * 4] = pv;
    }
    __syncthreads();

    float acc[4][4];
#pragma unroll
    for (int i = 0; i < 4; ++i)
#pragma unroll
      for (int cc = 0; cc < 4; ++cc) acc[i][cc] = 0.f;

#pragma unroll 2
    for (int kk = 0; kk < 64; kk += 4) {
      float4 pv[4], kv[4];
#pragma unroll
      for (int cc = 0; cc < 4; ++cc) pv[cc] = *(const float4*)&sP[(tx + 16 * cc) * 76 + kk];
#pragma unroll
      for (int i = 0; i < 4; ++i) kv[i] = *(const float4*)&sK[(ty * 4 + i) * 76 + kk];
#pragma unroll
      for (int i = 0; i < 4; ++i)
#pragma unroll
        for (int cc = 0; cc < 4; ++cc) {
          acc[i][cc] = fmaf(kv[i].x, pv[cc].x, acc[i][cc]);
          acc[i][cc] = fmaf(kv[i].y, pv[cc].y, acc[i][cc]);
          acc[i][cc] = fmaf(kv[i].z, pv[cc].z, acc[i][cc]);
          acc[i][cc] = fmaf(kv[i].w, pv[cc].w, acc[i][cc]);
        }
    }
#pragma unroll
    for (int cc = 0; cc < 4; ++cc) {
      if (tx + 16 * cc < jn) {
#pragma unroll
        for (int i = 0; i < 4; ++i) tmax = fmaxf(tmax, acc[i][cc]);
      }
    }
  }
#pragma unroll
  for (int off = 32; off; off >>= 1) tmax = fmaxf(tmax, __shfl_xor(tmax, off));
  if ((tid & 63) == 0) atomicMax(kmax, fenc(tmax * NORMF));
}

// ---------------------------------------------------------------------------
// Kernel B: context += k'^T V ; ksum += colsum(k'). 512 rows/block as 8x64.
// LDS ~57 KB -> 2 blocks/CU.
// ---------------------------------------------------------------------------
__global__ __launch_bounds__(256) void ctx_kernel(const float* __restrict__ k,
                                                  const float* __restrict__ v,
                                                  const float* __restrict__ proj,
                                                  const unsigned* __restrict__ kmaxp,
                                                  float* __restrict__ ctx,
                                                  float* __restrict__ ksum) {
  __shared__ float sK[64 * 76];   // K tile (stride 76); reused as k' (stride 68)
  __shared__ float sV[64 * 68];
  __shared__ float sP[64 * 76];
  __shared__ float sDiag[64];
  const int tid = threadIdx.x, tx = tid & 15, ty = tid >> 4;
  const int bh = blockIdx.x >> 3, c8 = blockIdx.x & 7;
  const float stab = fdec(*kmaxp);
  const float* kb = k + ((size_t)bh * NSEQ + (size_t)c8 * 512) * DDIM;
  const float* vb = v + ((size_t)bh * NSEQ + (size_t)c8 * 512) * DDIM;

  for (int c = 0; c < NCH; ++c) {
    const int j0 = c * 64, jn = min(64, MDIM - j0);
    __syncthreads();   // prev chunk fully done with sP/sK/sV
#pragma unroll
    for (int t = 0; t < 4; ++t) {
      int fid = tid + t * 256, jj = fid >> 4, d4 = fid & 15;
      float4 pv = (jj < jn) ? ((const float4*)(proj + (size_t)(j0 + jj) * DDIM))[d4]
                            : make_float4(0.f, 0.f, 0.f, 0.f);
      *(float4*)&sP[jj * 76 + d4 * 4] = pv;
    }

    float accC[4][4];
#pragma unroll
    for (int a = 0; a < 4; ++a)
#pragma unroll
      for (int b = 0; b < 4; ++b) accC[a][b] = 0.f;
    float ks = 0.f;

    for (int rt = 0; rt < 8; ++rt) {
      __syncthreads();   // prev rt outer-product reads done; sP visible (rt=0)
#pragma unroll
      for (int t = 0; t < 4; ++t) {
        int fid = tid + t * 256, r = fid >> 4, d4 = fid & 15;
        *(float4*)&sK[r * 76 + d4 * 4] = ((const float4*)(kb + (size_t)rt * 64 * DDIM))[fid];
        *(float4*)&sV[r * 68 + d4 * 4] = ((const float4*)(vb + (size_t)rt * 64 * DDIM))[fid];
      }
      __syncthreads();
      if (tid < 64) {
        float s = 0.f;
        for (int d = 0; d < 64; ++d) { float x = sK[tid * 76 + d]; s = fmaf(x, x, s); }
        sDiag[tid] = s * DIAGF;
      }

      float acc1[4][4];
#pragma unroll
      for (int i = 0; i < 4; ++i)
#pragma unroll
        for (int cc = 0; cc < 4; ++cc) acc1[i][cc] = 0.f;

#pragma unroll 2
      for (int kk = 0; kk < 64; kk += 4) {
        float4 pv[4], kv[4];
#pragma unroll
        for (int cc = 0; cc < 4; ++cc) pv[cc] = *(const float4*)&sP[(tx + 16 * cc) * 76 + kk];
#pragma unroll
        for (int i = 0; i < 4; ++i) kv[i] = *(const float4*)&sK[(ty * 4 + i) * 76 + kk];
#pragma unroll
        for (int i = 0; i < 4; ++i)
#pragma unroll
          for (int cc = 0; cc < 4; ++cc) {
            acc1[i][cc] = fmaf(kv[i].x, pv[cc].x, acc1[i][cc]);
            acc1[i][cc] = fmaf(kv[i].y, pv[cc].y, acc1[i][cc]);
            acc1[i][cc] = fmaf(kv[i].z, pv[cc].z, acc1[i][cc]);
            acc1[i][cc] = fmaf(kv[i].w, pv[cc].w, acc1[i][cc]);
          }
      }
      __syncthreads();   // GEMM1 + diag reads of sK done -> overwrite with k'
#pragma unroll
      for (int i = 0; i < 4; ++i) {
        const int r = ty * 4 + i;
        const float dg = sDiag[r];
#pragma unroll
        for (int cc = 0; cc < 4; ++cc) {
          const int cl = tx + 16 * cc;
          float kd = acc1[i][cc] * NORMF;
          float kp = (j0 + cl < MDIM) ? RATIO * (__expf(kd - dg - stab) + EPSF) : 0.f;
          sK[r * 68 + cl] = kp;
        }
      }
      __syncthreads();

#pragma unroll 2
      for (int r = 0; r < 64; ++r) {
        float4 kp4 = *(const float4*)&sK[r * 68 + ty * 4];
        float4 vv = *(const float4*)&sV[r * 68 + tx * 4];
#pragma unroll
        for (int b = 0; b < 4; ++b) {
          accC[0][b] = fmaf(kp4.x, ((const float*)&vv)[b], accC[0][b]);
          accC[1][b] = fmaf(kp4.y, ((const float*)&vv)[b], accC[1][b]);
          accC[2][b] = fmaf(kp4.z, ((const float*)&vv)[b], accC[2][b]);
          accC[3][b] = fmaf(kp4.w, ((const float*)&vv)[b], accC[3][b]);
        }
      }
      if (tid < 64) {
        float s = 0.f;
        for (int r = 0; r < 64; ++r) s += sK[r * 68 + tid];
        ks += s;
      }
    }
#pragma unroll
    for (int a = 0; a < 4; ++a) {
      const int jg = j0 + ty * 4 + a;
      if (jg < MDIM) {
#pragma unroll
        for (int b = 0; b < 4; ++b)
          atomicAdd(&ctx[((size_t)bh * MDIM + jg) * DDIM + tx * 4 + b], accC[a][b]);
      }
    }
    if (tid < 64 && j0 + tid < MDIM) atomicAdd(&ksum[(size_t)bh * MDIM + j0 + tid], ks);
  }
}

// ---------------------------------------------------------------------------
// Kernel C: q' (register-resident, 80 regs/thread) -> out = (q'*Dinv) @ ctx
// 64 rows/block; LDS ~41 KB. Row reduces via 16-lane shfl_xor.
// ---------------------------------------------------------------------------
__global__ __launch_bounds__(256) void out_kernel(const float* __restrict__ q,
                                                  const float* __restrict__ proj,
                                                  const float* __restrict__ ctx,
                                                  const float* __restrict__ ksum,
                                                  float* __restrict__ out) {
  __shared__ float smem[2 * 64 * 76];   // phase1: sQ | sP ; phase2: sQD | sCtx
  __shared__ float sDiag[64];
  __shared__ float sKs[320];
  float* sQ = smem;             // stride 76
  float* sP = smem + 64 * 76;   // stride 76
  float* sQD = smem;            // stride 68
  float* sCtx = smem + 64 * 76; // stride 68

  const int tid = threadIdx.x, tx = tid & 15, ty = tid >> 4;
  const int bh = blockIdx.x >> 6, rc = blockIdx.x & 63;
  const float* qb = q + ((size_t)bh * NSEQ + (size_t)rc * 64) * DDIM;

#pragma unroll
  for (int t = 0; t < 4; ++t) {
    int fid = tid + t * 256, r = fid >> 4, d4 = fid & 15;
    *(float4*)&sQ[r * 76 + d4 * 4] = ((const float4*)qb)[fid];
  }
  for (int t = tid; t < 320; t += 256) sKs[t] = (t < MDIM) ? ksum[(size_t)bh * MDIM + t] : 0.f;
  __syncthreads();
  if (tid < 64) {
    float s = 0.f;
    for (int d = 0; d < 64; ++d) { float x = sQ[tid * 76 + d]; s = fmaf(x, x, s); }
    sDiag[tid] = s * DIAGF;
  }

  float qp[4][NCH][4];   // [row i][chunk c][col cc], col j = c*64 + tx + 16*cc

#pragma unroll
  for (int c = 0; c < NCH; ++c) {
    const int j0 = c * 64, jn = min(64, MDIM - j0);
    __syncthreads();   // prev chunk GEMM1 reads of sP done
#pragma unroll
    for (int t = 0; t < 4; ++t) {
      int fid = tid + t * 256, jj = fid >> 4, d4 = fid & 15;
      float4 pv = (jj < jn) ? ((const float4*)(proj + (size_t)(j0 + jj) * DDIM))[d4]
                            : make_float4(0.f, 0.f, 0.f, 0.f);
      *(float4*)&sP[jj * 76 + d4 * 4] = pv;
    }
    __syncthreads();

    float acc[4][4];
#pragma unroll
    for (int i = 0; i < 4; ++i)
#pragma unroll
      for (int cc = 0; cc < 4; ++cc) acc[i][cc] = 0.f;

#pragma unroll 2
    for (int kk = 0; kk < 64; kk += 4) {
      float4 pv[4], kv[4];
#pragma unroll
      for (int cc = 0; cc < 4; ++cc) pv[cc] = *(const float4*)&sP[(tx + 16 * cc) * 76 + kk];
#pragma unroll
      for (int i = 0; i < 4; ++i) kv[i] = *(const float4*)&sQ[(ty * 4 + i) * 76 + kk];
#pragma unroll
      for (int i = 0; i < 4; ++i)
#pragma unroll
        for (int cc = 0; cc < 4; ++cc) {
          acc[i][cc] = fmaf(kv[i].x, pv[cc].x, acc[i][cc]);
          acc[i][cc] = fmaf(kv[i].y, pv[cc].y, acc[i][cc]);
          acc[i][cc] = fmaf(kv[i].z, pv[cc].z, acc[i][cc]);
          acc[i][cc] = fmaf(kv[i].w, pv[cc].w, acc[i][cc]);
        }
    }
#pragma unroll
    for (int i = 0; i < 4; ++i)
#pragma unroll
      for (int cc = 0; cc < 4; ++cc) qp[i][c][cc] = acc[i][cc] * NORMF;
  }

  // per-row max over all 266 cols: thread-local then 16-lane shfl reduce
  float mrow[4], di[4];
#pragma unroll
  for (int i = 0; i < 4; ++i) {
    float m = -1e30f;
#pragma unroll
    for (int c = 0; c < NCH; ++c)
#pragma unroll
      for (int cc = 0; cc < 4; ++cc) {
        const int j = c * 64 + tx + 16 * cc;
        if (j < MDIM) m = fmaxf(m, qp[i][c][cc]);
      }
    m = fmaxf(m, __shfl_xor(m, 1));
    m = fmaxf(m, __shfl_xor(m, 2));
    m = fmaxf(m, __shfl_xor(m, 4));
    m = fmaxf(m, __shfl_xor(m, 8));
    mrow[i] = m;
  }
  // exp + Dinv
#pragma unroll
  for (int i = 0; i < 4; ++i) {
    const float dg = sDiag[ty * 4 + i];
    float s = 0.f;
#pragma unroll
    for (int c = 0; c < NCH; ++c)
#pragma unroll
      for (int cc = 0; cc < 4; ++cc) {
        const int j = c * 64 + tx + 16 * cc;
        float val = (j < MDIM) ? RATIO * (__expf(qp[i][c][cc] - dg - mrow[i]) + EPSF) : 0.f;
        qp[i][c][cc] = val;
        s = fmaf(val, sKs[j], s);
      }
    s += __shfl_xor(s, 1);
    s += __shfl_xor(s, 2);
    s += __shfl_xor(s, 4);
    s += __shfl_xor(s, 8);
    di[i] = 1.0f / s;
  }

  // GEMM2: out = (q'*Dinv) @ ctx, chunk at a time through LDS
  float accO[4][4];
#pragma unroll
  for (int i = 0; i < 4; ++i)
#pragma unroll
    for (int b = 0; b < 4; ++b) accO[i][b] = 0.f;

#pragma unroll
  for (int c = 0; c < NCH; ++c) {
    const int j0 = c * 64, jn = min(64, MDIM - j0);
    __syncthreads();   // prev GEMM2 reads done (c=0: GEMM1 reads of smem done)
#pragma unroll
    for (int i = 0; i < 4; ++i) {
      const int r = ty * 4 + i;
#pragma unroll
      for (int cc = 0; cc < 4; ++cc) sQD[r * 68 + tx + 16 * cc] = qp[i][c][cc] * di[i];
    }
#pragma unroll
    for (int t = 0; t < 4; ++t) {
      int fid = tid + t * 256, r = fid >> 4, e4 = fid & 15;
      if (r < jn)
        *(float4*)&sCtx[r * 68 + e4 * 4] =
            ((const float4*)(ctx + ((size_t)bh * MDIM + j0 + r) * DDIM))[e4];
    }
    __syncthreads();

    const int jlim = (jn + 3) & ~3;   // 64 or 12; qd cols >=266 are zero
#pragma unroll 2
    for (int jj = 0; jj < jlim; jj += 4) {
      float4 qv[4], cv[4];
#pragma unroll
      for (int i = 0; i < 4; ++i) qv[i] = *(const float4*)&sQD[(ty * 4 + i) * 68 + jj];
#pragma unroll
      for (int u = 0; u < 4; ++u) cv[u] = *(const float4*)&sCtx[(jj + u) * 68 + tx * 4];
#pragma unroll
      for (int i = 0; i < 4; ++i)
#pragma unroll
        for (int b = 0; b < 4; ++b) {
          accO[i][b] = fmaf(qv[i].x, ((const float*)&cv[0])[b], accO[i][b]);
          accO[i][b] = fmaf(qv[i].y, ((const float*)&cv[1])[b], accO[i][b]);
          accO[i][b] = fmaf(qv[i].z, ((const float*)&cv[2])[b], accO[i][b]);
          accO[i][b] = fmaf(qv[i].w, ((const float*)&cv[3])[b], accO[i][b]);
        }
    }
  }

#pragma unroll
  for (int i = 0; i < 4; ++i) {
    const int r = ty * 4 + i;
    float4 o = make_float4(accO[i][0], accO[i][1], accO[i][2], accO[i][3]);
    *(float4*)&out[((size_t)bh * NSEQ + (size_t)rc * 64 + r) * DDIM + tx * 4] = o;
  }
}

extern "C" void kernel_launch(void* const* d_in, const int* in_sizes, int n_in,
                              void* d_out, int out_size, void* d_ws, size_t ws_size,
                              hipStream_t stream) {
  (void)in_sizes; (void)n_in; (void)out_size; (void)ws_size;
  const float* q = (const float*)d_in[0];
  const float* k = (const float*)d_in[1];
  const float* v = (const float*)d_in[2];
  const float* proj = (const float*)d_in[3];
  float* out = (float*)d_out;

  unsigned* kmax = (unsigned*)d_ws;
  float* ctx = (float*)((char*)d_ws + 256);
  float* ksum = (float*)((char*)d_ws + 256 + (size_t)BH * MDIM * DDIM * 4);
  const size_t ws_used = 256 + (size_t)BH * MDIM * DDIM * 4 + (size_t)BH * MDIM * 4;

  hipMemsetAsync(d_ws, 0, ws_used, stream);
  kmax_kernel<<<dim3(BH * 64), dim3(256), 0, stream>>>(k, proj, kmax);
  ctx_kernel<<<dim3(BH * 8), dim3(256), 0, stream>>>(k, v, proj, kmax, ctx, ksum);
  out_kernel<<<dim3(BH * 64), dim3(256), 0, stream>>>(q, proj, ctx, ksum, out);
}